// Round 12
// baseline (372.329 us; speedup 1.0000x reference)
//
#include <hip/hip_runtime.h>
#include <hip/hip_bf16.h>

#define D_MODEL 1024
#define NHEADS  16
#define DK      64
#define BATCH   4
#define SEQ     2048
#define M_TOT   (BATCH * SEQ)   // 8192

typedef __attribute__((ext_vector_type(8)))  __bf16 bf16x8;
typedef __attribute__((ext_vector_type(4)))  float  f32x4;
typedef __attribute__((ext_vector_type(16))) float  f32x16;
typedef unsigned short ushort_t;

static __device__ __forceinline__ unsigned int f2bf(float f) {
    union { float f; unsigned int i; } v; v.f = f;
    unsigned int x = v.i;
    return (x + 0x7fffu + ((x >> 16) & 1u)) >> 16;   // RNE, low 16 bits valid
}

// global -> LDS direct copy, 16 bytes per lane (global_load_lds_dwordx4).
static __device__ __forceinline__ void gl16(const void* g, void* lds_generic) {
    __attribute__((address_space(1))) void* gp =
        (__attribute__((address_space(1))) void*)(unsigned long long)g;
    __attribute__((address_space(3))) void* lp =
        (__attribute__((address_space(3))) void*)(unsigned int)(unsigned long long)lds_generic;
    __builtin_amdgcn_global_load_lds(gp, lp, 16, 0, 0);
}

// pack 8 fp32 -> 8 bf16 (one uint4) via v_cvt_pk_bf16_f32 (RNE), low16 = first
static __device__ __forceinline__ uint4 pack8(f32x4 lo, f32x4 hi) {
    uint4 u;
    asm("v_cvt_pk_bf16_f32 %0, %1, %2" : "=v"(u.x) : "v"(lo[0]), "v"(lo[1]));
    asm("v_cvt_pk_bf16_f32 %0, %1, %2" : "=v"(u.y) : "v"(lo[2]), "v"(lo[3]));
    asm("v_cvt_pk_bf16_f32 %0, %1, %2" : "=v"(u.z) : "v"(hi[0]), "v"(hi[1]));
    asm("v_cvt_pk_bf16_f32 %0, %1, %2" : "=v"(u.w) : "v"(hi[2]), "v"(hi[3]));
    return u;
}

// ---------------------------------------------------------------------------
// fp32 -> bf16 weights (4 matrices, grid.y selects)
// ---------------------------------------------------------------------------
__global__ __launch_bounds__(256) void cvt_w4(
    const float* __restrict__ w0, const float* __restrict__ w1,
    const float* __restrict__ w2, const float* __restrict__ w3,
    ushort_t* __restrict__ o0, ushort_t* __restrict__ o1,
    ushort_t* __restrict__ o2, ushort_t* __restrict__ o3, int n8)
{
    const float* w; ushort_t* o;
    switch (blockIdx.y) {
        case 0: w = w0; o = o0; break;
        case 1: w = w1; o = o1; break;
        case 2: w = w2; o = o2; break;
        default: w = w3; o = o3; break;
    }
    int i = blockIdx.x * blockDim.x + threadIdx.x;
    if (i >= n8) return;
    const float4* p = (const float4*)w + (size_t)i * 2;
    float4 a = p[0], b = p[1];
    uint4 u;
    u.x = f2bf(a.x) | (f2bf(a.y) << 16);
    u.y = f2bf(a.z) | (f2bf(a.w) << 16);
    u.z = f2bf(b.x) | (f2bf(b.y) << 16);
    u.w = f2bf(b.z) | (f2bf(b.w) << 16);
    *((uint4*)o + i) = u;
}

// ---------------------------------------------------------------------------
// QKV NT GEMM with fp32 A staged via global_load_lds (NO separate cvt_in3).
// A (q/k/v input) is fp32 [M,1024]; staged fp32 into LDS by the SAME gl16 DMA
// path (4 chunks/lane), converted to bf16 fragments at the LDS->reg step
// (4 cvt_pk per fragment).  B is bf16 weights (cvt_w4).  fp32-chunk swizzle:
// 16 chunks of 4 fp32 per row; physical = logical ^ (row&15).
// z==0 -> Q bf16 [B,H,T,64] PRE-SCALED by 0.125*log2(e); z==1 -> K;
// z==2 -> V^T bf16 [BH,64,T].
// 128x128 tile, BK=64, 8 waves/512 thr, LDS 96 KiB (1 block/CU).
// 2-phase double-buffer, issue-early gl16 prefetch, XCD-aware swizzle.
// ---------------------------------------------------------------------------
__global__ __launch_bounds__(512) void gemm_qkv(
    const float* __restrict__ A0, const float* __restrict__ A1,
    const float* __restrict__ A2,
    const ushort_t* __restrict__ B0, const ushort_t* __restrict__ B1,
    const ushort_t* __restrict__ B2,
    const float* __restrict__ b0, const float* __restrict__ b1,
    const float* __restrict__ b2,
    ushort_t* __restrict__ O0, ushort_t* __restrict__ O1,
    ushort_t* __restrict__ O2)
{
    const int z = blockIdx.z;
    const float* Af    = (z == 0) ? A0 : (z == 1) ? A1 : A2;
    const ushort_t* Bt = (z == 0) ? B0 : (z == 1) ? B1 : B2;
    const float* bias  = (z == 0) ? b0 : (z == 1) ? b1 : b2;
    ushort_t* Out      = (z == 0) ? O0 : (z == 1) ? O1 : O2;
    const float oscale = (z == 0) ? 0.18033688f : 1.0f;  // Q exp2-domain prescale

    __shared__ float    sA[2][128 * 64];    // fp32 A tile, 32 KiB each
    __shared__ ushort_t sB[2][128 * 64];    // bf16 B tile, 16 KiB each
    const int K    = 1024;
    const int tid  = threadIdx.x;
    const int lane = tid & 63;
    const int wave = tid >> 6;              // 0..7

    // XCD-aware bijective swizzle: grid (x=8, y=64) -> 512 wgs, 64 per XCD.
    const int flat = (int)blockIdx.x + 8 * (int)blockIdx.y;
    const int nf   = (flat & 7) * 64 + (flat >> 3);
    const int m0   = (nf >> 3) * 128;
    const int n0   = (nf & 7) * 128;

    const int wrow = (wave >> 2) * 64;      // 2 wave-rows x 64
    const int wcol = (wave & 3) * 32;       // 4 wave-cols x 32
    const int l15  = lane & 15;
    const int quad = lane >> 4;

    // A: 2048 chunks of 4 fp32 (16 B); 4 per thread.  physical = c&15,
    // source logical = (c&15)^(row&15)  ->  phys p holds logical p^(row&15).
    size_t aoffs[4];
#pragma unroll
    for (int i = 0; i < 4; i++) {
        int c = tid + 512 * i;              // 0..2047
        int row = c >> 4;
        int ch  = (c & 15) ^ (row & 15);
        aoffs[i] = (size_t)(m0 + row) * K + ch * 4;
    }
    // B: 1024 chunks of 8 bf16 (16 B); 2 per thread (r10-proven layout).
    size_t boffs[2];
#pragma unroll
    for (int i = 0; i < 2; i++) {
        int c = tid + 512 * i;
        int row = c >> 3;
        int ch  = (c & 7) ^ (row & 7);
        boffs[i] = (size_t)(n0 + row) * K + ch * 8;
    }

    f32x4 acc[4][2];
#pragma unroll
    for (int i = 0; i < 4; i++)
#pragma unroll
        for (int j = 0; j < 2; j++)
#pragma unroll
            for (int r = 0; r < 4; r++) acc[i][j][r] = 0.0f;

    auto stage = [&](int buf, int kt) {
#pragma unroll
        for (int i = 0; i < 4; i++)
            gl16(Af + aoffs[i] + kt, &sA[buf][(tid + 512 * i) * 4]);
#pragma unroll
        for (int i = 0; i < 2; i++)
            gl16(Bt + boffs[i] + kt, &sB[buf][(tid + 512 * i) * 8]);
    };

    stage(0, 0);
    asm volatile("s_waitcnt vmcnt(0)");
    __syncthreads();
    int cur = 0;

    for (int kt = 0; kt < K; kt += 64) {
        if (kt + 64 < K) stage(cur ^ 1, kt + 64);   // issue-early prefetch

#pragma unroll
        for (int kk = 0; kk < 2; kk++) {
            const int chp8 = kk * 4 + quad;          // logical 8-elem chunk
            bf16x8 afr[4], bfr[2];
#pragma unroll
            for (int i = 0; i < 4; i++) {
                int r = wrow + i * 16 + l15;         // r & 15 == l15
                const float* ar = &sA[cur][r * 64];
                f32x4 a0 = *(const f32x4*)&ar[((2 * chp8) ^ l15) * 4];
                f32x4 a1 = *(const f32x4*)&ar[((2 * chp8 + 1) ^ l15) * 4];
                union { uint4 u; bf16x8 v; } cvt;
                cvt.u = pack8(a0, a1);
                afr[i] = cvt.v;
            }
#pragma unroll
            for (int j = 0; j < 2; j++)
                bfr[j] = *(const bf16x8*)(&sB[cur][(wcol + j * 16 + l15) * 64 +
                                                   ((chp8 ^ (l15 & 7)) * 8)]);
#pragma unroll
            for (int i = 0; i < 4; i++)
#pragma unroll
                for (int j = 0; j < 2; j++)
                    acc[i][j] = __builtin_amdgcn_mfma_f32_16x16x32_bf16(
                        afr[i], bfr[j], acc[i][j], 0, 0, 0);
        }

        asm volatile("s_waitcnt vmcnt(0)");
        __syncthreads();
        cur ^= 1;
    }

    if (z == 2) {
        // write V^T [BH, 64, T]: 4 consecutive-t values -> 8B store
#pragma unroll
        for (int j = 0; j < 2; j++) {
            int col  = n0 + wcol + j * 16 + l15;
            float bv = bias[col];
            int h = col >> 6, dk = col & 63;
#pragma unroll
            for (int i = 0; i < 4; i++) {
                int row0 = m0 + wrow + i * 16 + quad * 4;
                int b = row0 >> 11, t0 = row0 & 2047;
                ushort_t pk[4];
#pragma unroll
                for (int r = 0; r < 4; r++)
                    pk[r] = (ushort_t)f2bf(acc[i][j][r] + bv);
                *(uint2*)&Out[((size_t)(b * 16 + h) * 64 + dk) * SEQ + t0] =
                    *(const uint2*)pk;
            }
        }
        return;
    }

#pragma unroll
    for (int j = 0; j < 2; j++) {
        int col  = n0 + wcol + j * 16 + l15;
        float bv = bias[col];
        int h = col >> 6, dk = col & 63;
#pragma unroll
        for (int i = 0; i < 4; i++) {
#pragma unroll
            for (int r = 0; r < 4; r++) {
                int row = m0 + wrow + i * 16 + quad * 4 + r;
                float o = (acc[i][j][r] + bv) * oscale;
                int b = row >> 11, t = row & 2047;
                Out[((size_t)(b * 16 + h) * 2048 + t) * 64 + dk] = (ushort_t)f2bf(o);
            }
        }
    }
}

// ---------------------------------------------------------------------------
// Output-projection NT GEMM (r10-proven bf16/gl16 form).
// A = bf16 attn-out [M,1024]; B = bf16 Wo (cvt_w4); Out fp32 [M,1024].
// 128x128 tile, BK=64, 8 waves/512 thr, 64 KiB LDS (2 blocks/CU).
// ---------------------------------------------------------------------------
__global__ __launch_bounds__(512) void gemm_out(
    const ushort_t* __restrict__ A,
    const ushort_t* __restrict__ Bt,
    const float* __restrict__ bias,
    float* __restrict__ Out)
{
    __shared__ ushort_t sA[2][128 * 64];
    __shared__ ushort_t sB[2][128 * 64];
    const int K    = 1024;
    const int tid  = threadIdx.x;
    const int lane = tid & 63;
    const int wave = tid >> 6;

    const int flat = (int)blockIdx.x + 8 * (int)blockIdx.y;
    const int nf   = (flat & 7) * 64 + (flat >> 3);
    const int m0   = (nf >> 3) * 128;
    const int n0   = (nf & 7) * 128;

    const int wrow = (wave >> 2) * 64;
    const int wcol = (wave & 3) * 32;
    const int l15  = lane & 15;
    const int quad = lane >> 4;
    const int swz  = l15 & 7;

    size_t aoffs[2], boffs[2];
#pragma unroll
    for (int i = 0; i < 2; i++) {
        int c = tid + 512 * i;
        int row = c >> 3;
        int ch  = (c & 7) ^ (row & 7);
        aoffs[i] = (size_t)(m0 + row) * K + ch * 8;
        boffs[i] = (size_t)(n0 + row) * K + ch * 8;
    }

    f32x4 acc[4][2];
#pragma unroll
    for (int i = 0; i < 4; i++)
#pragma unroll
        for (int j = 0; j < 2; j++)
#pragma unroll
            for (int r = 0; r < 4; r++) acc[i][j][r] = 0.0f;

    auto stage = [&](int buf, int kt) {
#pragma unroll
        for (int i = 0; i < 2; i++) {
            int c = tid + 512 * i;
            gl16(A + aoffs[i] + kt, &sA[buf][c * 8]);
            gl16(Bt + boffs[i] + kt, &sB[buf][c * 8]);
        }
    };

    stage(0, 0);
    asm volatile("s_waitcnt vmcnt(0)");
    __syncthreads();
    int cur = 0;

    for (int kt = 0; kt < K; kt += 64) {
        if (kt + 64 < K) stage(cur ^ 1, kt + 64);

#pragma unroll
        for (int kk = 0; kk < 2; kk++) {
            bf16x8 afr[4], bfr[2];
            const int chp = ((kk * 4 + quad) ^ swz) * 8;
#pragma unroll
            for (int i = 0; i < 4; i++)
                afr[i] = *(const bf16x8*)(&sA[cur][(wrow + i * 16 + l15) * 64 + chp]);
#pragma unroll
            for (int j = 0; j < 2; j++)
                bfr[j] = *(const bf16x8*)(&sB[cur][(wcol + j * 16 + l15) * 64 + chp]);
#pragma unroll
            for (int i = 0; i < 4; i++)
#pragma unroll
                for (int j = 0; j < 2; j++)
                    acc[i][j] = __builtin_amdgcn_mfma_f32_16x16x32_bf16(
                        afr[i], bfr[j], acc[i][j], 0, 0, 0);
        }

        asm volatile("s_waitcnt vmcnt(0)");
        __syncthreads();
        cur ^= 1;
    }

#pragma unroll
    for (int j = 0; j < 2; j++) {
        int col  = n0 + wcol + j * 16 + l15;
        float bv = bias[col];
#pragma unroll
        for (int i = 0; i < 4; i++) {
#pragma unroll
            for (int r = 0; r < 4; r++) {
                int row = m0 + wrow + i * 16 + quad * 4 + r;
                Out[(size_t)row * 1024 + col] = acc[i][j][r] + bv;
            }
        }
    }
}

// ---------------------------------------------------------------------------
// Causal flash attention (r10-proven, byte-identical).
// ---------------------------------------------------------------------------
__global__ __launch_bounds__(256, 2) void attn_causal(
    const ushort_t* __restrict__ Q,
    const ushort_t* __restrict__ Km,
    const ushort_t* __restrict__ Vt,
    ushort_t* __restrict__ O)
{
    __shared__ ushort_t sK[2][64 * 64];     // [kv64][d64], chunk-XOR swizzled
    __shared__ ushort_t sVt[2][64 * 64];    // [d64][kv64], chunk-XOR swizzled

    const int tid  = threadIdx.x;
    const int lane = tid & 63;
    const int wave = tid >> 6;
    const int l31  = lane & 31;
    const int hi   = lane >> 5;
    const int bh   = blockIdx.x;
    const int qtile = 15 - (int)blockIdx.y; // longest blocks dispatch first
    const size_t base = (size_t)bh * SEQ * 64;

    size_t ksrc[2], vsrc[2];
#pragma unroll
    for (int i = 0; i < 2; i++) {
        int c  = tid + 256 * i;             // 0..511
        int kr = c >> 3, kc = (c & 7) ^ (kr & 7);
        ksrc[i] = base + (size_t)kr * 64 + kc * 8;      // + s*64*64
        int vr = c >> 3, vc = (c & 7) ^ (vr & 7);
        vsrc[i] = base + (size_t)vr * SEQ + vc * 8;     // + s*64
    }

    bf16x8 qfr[4];
    f32x16 oacc[2];
    float  ls[4];

#pragma unroll
    for (int j = 0; j < 2; j++)
#pragma unroll
        for (int r = 0; r < 16; r++) oacc[j][r] = 0.0f;
#pragma unroll
    for (int r = 0; r < 4; r++) ls[r] = 0.0f;

    {
        const size_t qrow = base + (size_t)(qtile * 128 + wave * 32 + l31) * 64;
#pragma unroll
        for (int kk = 0; kk < 4; kk++)
            qfr[kk] = *(const bf16x8*)&Q[qrow + kk * 16 + hi * 8];
    }

    auto stage = [&](int buf, int s) {      // s in 64-kv units
        const size_t ko = (size_t)s * 64 * 64;
        const size_t vo = (size_t)s * 64;
#pragma unroll
        for (int i = 0; i < 2; i++) {
            int c = tid + 256 * i;
            gl16(Km + ksrc[i] + ko, &sK[buf][c * 8]);
            gl16(Vt + vsrc[i] + vo, &sVt[buf][c * 8]);
        }
    };

    auto compute = [&](int cur, int s64) {
        const ushort_t* kb_ = &sK[cur][0];
        const ushort_t* vb_ = &sVt[cur][0];
        const int kv0   = s64 * 64;
        const int qgmin = qtile * 128 + wave * 32;
        const int qg    = qgmin + l31;

        f32x16 sacc[2];
#pragma unroll
        for (int b = 0; b < 2; b++) {
            if (kv0 + b * 32 > qgmin + 31) continue;      // fully masked
#pragma unroll
            for (int r = 0; r < 16; r++) sacc[b][r] = 0.0f;
            const int krow = b * 32 + l31;
            const int ksw  = krow & 7;
            __builtin_amdgcn_s_setprio(1);
#pragma unroll
            for (int kk = 0; kk < 4; kk++) {
                bf16x8 afr = *(const bf16x8*)&kb_[krow * 64 + (((kk * 2 + hi) ^ ksw) * 8)];
                sacc[b] = __builtin_amdgcn_mfma_f32_32x32x16_bf16(afr, qfr[kk], sacc[b], 0, 0, 0);
            }
            __builtin_amdgcn_s_setprio(0);
        }

#pragma unroll
        for (int b = 0; b < 2; b++) {
            if (kv0 + b * 32 > qgmin + 31) continue;      // fully masked
            const bool maskb = (kv0 + b * 32 + 31) > qgmin;

            float p[16];
#pragma unroll
            for (int r = 0; r < 16; r++) {
                float v = sacc[b][r];
                if (maskb) {
                    int kvg = kv0 + b * 32 + (r & 3) + 8 * (r >> 2) + 4 * hi;
                    if (kvg > qg) v = -INFINITY;
                }
                float e = __builtin_amdgcn_exp2f(v);
                p[r] = e;
                ls[r & 3] += e;                  // 4 short chains
            }

            unsigned w[8];
#pragma unroll
            for (int t = 0; t < 4; t++) {
                asm("v_cvt_pk_bf16_f32 %0, %1, %2"
                    : "=v"(w[2 * t]) : "v"(p[4 * t]), "v"(p[4 * t + 1]));
                asm("v_cvt_pk_bf16_f32 %0, %1, %2"
                    : "=v"(w[2 * t + 1]) : "v"(p[4 * t + 2]), "v"(p[4 * t + 3]));
            }

#pragma unroll
            for (int kb = 0; kb < 2; kb++) {     // 16-kv PV k-chunk
                unsigned aA = w[kb * 4 + 0], bA = w[kb * 4 + 2];
                unsigned aB = w[kb * 4 + 1], bB = w[kb * 4 + 3];
                asm("v_permlane32_swap_b32 %0, %1" : "+v"(aA), "+v"(bA));
                asm("v_permlane32_swap_b32 %0, %1" : "+v"(aB), "+v"(bB));
                union { unsigned u[4]; bf16x8 v8; } fr;
                fr.u[0] = aA; fr.u[1] = aB; fr.u[2] = bA; fr.u[3] = bB;
                __builtin_amdgcn_s_setprio(1);
#pragma unroll
                for (int j = 0; j < 2; j++) {    // 32-d output block
                    const int vrow = j * 32 + l31;
                    bf16x8 bfr = *(const bf16x8*)&vb_[
                        vrow * 64 + (((b * 4 + kb * 2 + hi) ^ (vrow & 7)) * 8)];
                    oacc[j] = __builtin_amdgcn_mfma_f32_32x32x16_bf16(
                        fr.v8, bfr, oacc[j], 0, 0, 0);
                }
                __builtin_amdgcn_s_setprio(0);
            }
        }
    };

    const int send = 2 * qtile + 1;
    stage(0, 0);
    asm volatile("s_waitcnt vmcnt(0)");
    __syncthreads();
    int cur = 0;
    for (int u = 0; u <= send; ++u) {
        if (u < send) stage(cur ^ 1, u + 1);          // issue-early prefetch
        compute(cur, u);
        asm volatile("s_waitcnt vmcnt(0)");
        __syncthreads();
        cur ^= 1;
    }

    const int ob = bh >> 4, oh = bh & 15;
    {
        float lsum = (ls[0] + ls[1]) + (ls[2] + ls[3]);
        float tot = lsum + __shfl_xor(lsum, 32);
        float inv = 1.0f / tot;
#pragma unroll
        for (int r = 0; r < 16; r++) {
            int qloc = (r & 3) + 8 * (r >> 2) + 4 * hi;   // O row for this reg
            float invr = __shfl(inv, qloc);
            int qg2 = qtile * 128 + wave * 32 + qloc;
#pragma unroll
            for (int j = 0; j < 2; j++) {
                O[((size_t)(ob * SEQ) + qg2) * 1024 + oh * 64 + j * 32 + l31] =
                    (ushort_t)f2bf(oacc[j][r] * invr);
            }
        }
    }
}

// ---------------------------------------------------------------------------
extern "C" void kernel_launch(void* const* d_in, const int* in_sizes, int n_in,
                              void* d_out, int out_size, void* d_ws, size_t ws_size,
                              hipStream_t stream) {
    const float* q_in = (const float*)d_in[0];
    const float* k_in = (const float*)d_in[1];
    const float* v_in = (const float*)d_in[2];
    // d_in[3] = mask — causality implemented directly
    const float* Wq = (const float*)d_in[4];
    const float* bq = (const float*)d_in[5];
    const float* Wk = (const float*)d_in[6];
    const float* bk = (const float*)d_in[7];
    const float* Wv = (const float*)d_in[8];
    const float* bv = (const float*)d_in[9];
    const float* Wo = (const float*)d_in[10];
    const float* bo = (const float*)d_in[11];

    ushort_t* ws = (ushort_t*)d_ws;
    const size_t TEN = (size_t)M_TOT * D_MODEL;   // 8M elements
    const size_t WEL = (size_t)D_MODEL * D_MODEL; // 1M elements
    ushort_t* WqB = ws;
    ushort_t* WkB = WqB + WEL;
    ushort_t* WvB = WkB + WEL;
    ushort_t* WoB = WvB + WEL;
    ushort_t* qw  = WoB + WEL;          // [B,H,T,64] (pre-scaled)
    ushort_t* kw  = qw + TEN;
    ushort_t* vw  = kw + TEN;           // V^T [BH,64,T]
    ushort_t* ow  = vw + TEN;           // attn out [B*T,1024]

    const int n8_w = (int)(WEL / 8);

    cvt_w4<<<dim3(n8_w / 256, 4), dim3(256), 0, stream>>>(
        Wq, Wk, Wv, Wo, WqB, WkB, WvB, WoB, n8_w);

    // fused QKV projections — fp32 inputs staged via gl16, no cvt_in3 pass
    gemm_qkv<<<dim3(8, 64, 3), dim3(512), 0, stream>>>(
        q_in, k_in, v_in, WqB, WkB, WvB, bq, bk, bv, qw, kw, vw);

    attn_causal<<<dim3(BATCH * NHEADS, 16), dim3(256), 0, stream>>>(qw, kw, vw, ow);

    gemm_out<<<dim3(8, 64, 1), dim3(512), 0, stream>>>(ow, WoB, bo, (float*)d_out);
}